// Round 15
// baseline (427.080 us; speedup 1.0000x reference)
//
#include <hip/hip_runtime.h>

#define EPS_LN 1e-5f
typedef unsigned int uint;

using bf16x8 = __attribute__((ext_vector_type(8))) short;
using f32x4  = __attribute__((ext_vector_type(4))) float;

__device__ inline float bf2f(ushort h){ return __uint_as_float(((uint)h) << 16); }
__device__ inline ushort f2bf(float f){
  uint u = __float_as_uint(f);
  u += 0x7fffu + ((u >> 16) & 1u);   // round-to-nearest-even
  return (ushort)(u >> 16);
}

__device__ inline void gload_lds16(const ushort* g, ushort* l){
  __builtin_amdgcn_global_load_lds(
      (const __attribute__((address_space(1))) uint*)g,
      (__attribute__((address_space(3))) uint*)l, 16, 0, 0);
}

#define POOL_Q 32   // chunks per graph in k_pool

// ---- mega-prep: cast x, transpose/cast W1-3, deg histogram, bounds, pool/flag zeroing ----
__global__ void k_prep(const float* __restrict__ x, ushort* __restrict__ x_bf,
                       const float* __restrict__ W1, ushort* __restrict__ W1t,
                       const float* __restrict__ W2, ushort* __restrict__ W2t,
                       const float* __restrict__ W3, ushort* __restrict__ W3t,
                       const int* __restrict__ ei, int* __restrict__ deg,
                       const int* __restrict__ batch, int* __restrict__ pos,
                       float* __restrict__ pool_sum, uint* __restrict__ pool_max,
                       int* __restrict__ flag,
                       int N, int E, int G, int NB){
  int i = blockIdx.x * 256 + threadIdx.x;
  const int c0 = N * 32;                    // float4 quads of x
  if (i < c0){
    float4 v = reinterpret_cast<const float4*>(x)[i];
    ushort4 o; o.x = f2bf(v.x); o.y = f2bf(v.y); o.z = f2bf(v.z); o.w = f2bf(v.w);
    reinterpret_cast<ushort4*>(x_bf)[i] = o;
    return;
  }
  i -= c0;
  if (i < 256 * 128){                       // W1t[n*128+k] = W1[k*256+n]
    int n = i >> 7, k = i & 127;
    W1t[i] = f2bf(W1[(size_t)k * 256 + n]);
    return;
  }
  i -= 256 * 128;
  if (i < 256 * 256){                       // W2t[n*256+k] = W2[k*256+n]
    int n = i >> 8, k = i & 255;
    W2t[i] = f2bf(W2[(size_t)k * 256 + n]);
    return;
  }
  i -= 256 * 256;
  if (i < 128 * 256){                       // W3t[n*256+k] = W3[k*128+n]
    int n = i >> 8, k = i & 255;
    W3t[i] = f2bf(W3[(size_t)k * 128 + n]);
    return;
  }
  i -= 128 * 256;
  if (i < E + N){                           // degree histogram (deg pre-zeroed by memset)
    int dst = (i < E) ? ei[E + i] : (i - E);
    atomicAdd(&deg[dst], 1);
    return;
  }
  i -= E + N;
  if (i < G * 128){                         // zero pool buffers + flag + graph bounds
    pool_sum[i] = 0.f;
    pool_max[i] = 0u;
    if (i < NB) flag[i] = 0;
    if (i <= G){                            // first idx with batch[idx] >= i
      int lo = 0, hi = N;
      while (lo < hi){
        int mid = (lo + hi) >> 1;
        if (batch[mid] < i) lo = mid + 1; else hi = mid;
      }
      pos[i] = lo;
    }
  }
}

// ---------------- single-pass decoupled-lookback scan: deg -> row_ptr, cursor --------------
__global__ __launch_bounds__(1024) void k_scanall(const int* __restrict__ deg,
    int* __restrict__ row_ptr, int* __restrict__ cursor,
    int* __restrict__ pref, int* __restrict__ flag, int n){
  __shared__ int wsum[16];
  __shared__ int prev_s;
  const int b = (int)blockIdx.x;
  const int t = (int)threadIdx.x, lane = t & 63, w = t >> 6;
  int i = b * 1024 + t;
  int v = (i < n) ? deg[i] : 0;
  int s = v;
  #pragma unroll
  for (int off = 1; off < 64; off <<= 1){ int u = __shfl_up(s, off); if (lane >= off) s += u; }
  if (lane == 63) wsum[w] = s;
  __syncthreads();
  if (w == 0 && lane < 16){
    int sc = wsum[lane];
    #pragma unroll
    for (int off = 1; off < 16; off <<= 1){ int u = __shfl_up(sc, off); if (lane >= off) sc += u; }
    wsum[lane] = sc;
  }
  __syncthreads();
  const int local_inc = (w ? wsum[w - 1] : 0) + s;      // inclusive within block
  if (t == 0){
    int prev = 0;
    if (b > 0){
      while (atomicCAS(&flag[b - 1], 1, 1) == 0){}
      __threadfence();
      prev = pref[b - 1];
    }
    pref[b] = prev + wsum[15];
    __threadfence();
    atomicExch(&flag[b], 1);
    prev_s = prev;
  }
  __syncthreads();
  const int prefix = prev_s + local_inc;
  if (i < n){ row_ptr[i + 1] = prefix; cursor[i] = prefix - v; }
  if (i == 0) row_ptr[0] = 0;
}

__global__ void k_scatter(const int* __restrict__ ei, int* __restrict__ cursor,
                          int* __restrict__ csr_src, int E, int N){
  int e = blockIdx.x * 256 + threadIdx.x;
  if (e >= E + N) return;
  int src, dst;
  if (e < E){ src = ei[e]; dst = ei[E + e]; } else { src = dst = e - E; }
  int pos = atomicAdd(&cursor[dst], 1);
  csr_src[pos] = src;
}

// ---------------- MFMA GEMM (BK=64, global_load_lds staging) + fused attn-coef epilogue ----
template<int K, int N, int H>
__global__ __launch_bounds__(256, 4) void k_mm(const ushort* __restrict__ A,
                                               const ushort* __restrict__ Wt,
                                               ushort* __restrict__ out,
                                               const float* __restrict__ asrc,
                                               const float* __restrict__ adst,
                                               float* __restrict__ al, float* __restrict__ ar,
                                               int M)
{
  constexpr int BANDS = (N / H) / 64;   // 64-col bands per head: 1 (H=4,N=256) or 2 (H=1,N=128)
  __shared__ __align__(16) ushort ldsA[128 * 64];
  __shared__ __align__(16) ushort ldsB[128 * 64];

  const int t = (int)threadIdx.x;
  const int lane = t & 63;
  const int w = t >> 6;
  const int wm = w >> 1, wn = w & 1;
  const int row0 = blockIdx.x * 128;
  const int n0 = blockIdx.y * 128;
  const int growR = w * 8 + (lane >> 3);     // row-in-round 0..31
  const int gcolA = (lane & 7) * 8;          // col elems 0..56

  f32x4 acc[4][4];
  #pragma unroll
  for (int mt = 0; mt < 4; mt++)
    #pragma unroll
    for (int nt = 0; nt < 4; nt++)
      acc[mt][nt] = (f32x4){0.f, 0.f, 0.f, 0.f};

  #pragma unroll
  for (int kt = 0; kt < K / 64; kt++){
    if (kt) __syncthreads();                 // all ds_reads of prev tile drained
    #pragma unroll
    for (int r = 0; r < 4; r++){
      int ga = row0 + r * 32 + growR; if (ga > M - 1) ga = M - 1;
      int gb = n0 + r * 32 + growR;          // N dims exact multiples of 128
      gload_lds16(&A [(size_t)ga * K + kt * 64 + gcolA], ldsA + r * 2048 + w * 512);
      gload_lds16(&Wt[(size_t)gb * K + kt * 64 + gcolA], ldsB + r * 2048 + w * 512);
    }
    __syncthreads();                         // vmcnt(0) drained by barrier semantics

    #pragma unroll
    for (int ks = 0; ks < 2; ks++){
      bf16x8 af[4], bfr[4];
      const int kb8 = ks * 4 + (lane >> 4);  // 0..7
      #pragma unroll
      for (int mt = 0; mt < 4; mt++){
        int arow = wm * 64 + mt * 16 + (lane & 15);
        af[mt]  = *reinterpret_cast<const bf16x8*>(&ldsA[arow * 64 + kb8 * 8]);
        int brow = wn * 64 + mt * 16 + (lane & 15);
        bfr[mt] = *reinterpret_cast<const bf16x8*>(&ldsB[brow * 64 + kb8 * 8]);
      }
      #pragma unroll
      for (int mt = 0; mt < 4; mt++)
        #pragma unroll
        for (int nt = 0; nt < 4; nt++)
          acc[mt][nt] = __builtin_amdgcn_mfma_f32_16x16x32_bf16(af[mt], bfr[nt], acc[mt][nt], 0, 0, 0);
    }
  }

  // ---- epilogue 1: C store (C/D map col=lane&15, row=(lane>>4)*4+r, m89-verified) ----
  #pragma unroll
  for (int mt = 0; mt < 4; mt++){
    const int grow_b = row0 + wm * 64 + mt * 16 + (lane >> 4) * 4;
    #pragma unroll
    for (int nt = 0; nt < 4; nt++){
      const int gcol = n0 + wn * 64 + nt * 16 + (lane & 15);
      #pragma unroll
      for (int r = 0; r < 4; r++){
        int grow = grow_b + r;
        if (grow < M) out[(size_t)grow * N + gcol] = f2bf(acc[mt][nt][r]);
      }
    }
  }

  // ---- epilogue 2: fused attention coefficients from f32 accumulators ----
  float av[4], bv[4];
  #pragma unroll
  for (int nt = 0; nt < 4; nt++){
    int col = n0 + wn * 64 + nt * 16 + (lane & 15);
    av[nt] = asrc[col]; bv[nt] = adst[col];
  }
  float paA[4][4], pbA[4][4];     // [mt][r], reduced over the 64-col band
  #pragma unroll
  for (int mt = 0; mt < 4; mt++){
    #pragma unroll
    for (int r = 0; r < 4; r++){
      float pa = acc[mt][0][r] * av[0] + acc[mt][1][r] * av[1]
               + acc[mt][2][r] * av[2] + acc[mt][3][r] * av[3];
      float pb = acc[mt][0][r] * bv[0] + acc[mt][1][r] * bv[1]
               + acc[mt][2][r] * bv[2] + acc[mt][3][r] * bv[3];
      #pragma unroll
      for (int off = 1; off < 16; off <<= 1){ pa += __shfl_xor(pa, off); pb += __shfl_xor(pb, off); }
      paA[mt][r] = pa; pbA[mt][r] = pb;
    }
  }
  if constexpr (BANDS == 1){
    const int h = (n0 + wn * 64) / (N / H);
    if ((lane & 15) == 0){
      #pragma unroll
      for (int mt = 0; mt < 4; mt++){
        #pragma unroll
        for (int r = 0; r < 4; r++){
          int row = row0 + wm * 64 + mt * 16 + (lane >> 4) * 4 + r;
          if (row < M){
            al[(size_t)row * H + h] = paA[mt][r];
            ar[(size_t)row * H + h] = pbA[mt][r];
          }
        }
      }
    }
  } else {
    // H=1: two column bands (wn=0,1) sum into the same head; combine via LDS
    __syncthreads();                          // ldsA free for reuse
    float* fl = reinterpret_cast<float*>(ldsA);   // 256 floats
    if (wn == 0 && (lane & 15) == 0){
      #pragma unroll
      for (int mt = 0; mt < 4; mt++){
        #pragma unroll
        for (int r = 0; r < 4; r++){
          int rl = wm * 64 + mt * 16 + (lane >> 4) * 4 + r;
          fl[rl] = paA[mt][r]; fl[128 + rl] = pbA[mt][r];
        }
      }
    }
    __syncthreads();
    if (wn == 1 && (lane & 15) == 0){
      #pragma unroll
      for (int mt = 0; mt < 4; mt++){
        #pragma unroll
        for (int r = 0; r < 4; r++){
          int rl = wm * 64 + mt * 16 + (lane >> 4) * 4 + r;
          int row = row0 + rl;
          if (row < M){
            al[row] = fl[rl] + paA[mt][r];
            ar[row] = fl[128 + rl] + pbA[mt][r];
          }
        }
      }
    }
  }
}

// ---- gather helpers: one edge row contribution ----
template<int DIM>
__device__ inline void gstep4(const char* __restrict__ xlb, int laneB, int s, float p, float* acc){
  uint2 v = *reinterpret_cast<const uint2*>(xlb + (size_t)((uint)s * (uint)(DIM * 2)) + laneB);
  acc[0] = fmaf(p, __uint_as_float(v.x << 16), acc[0]);
  acc[1] = fmaf(p, __uint_as_float(v.x & 0xffff0000u), acc[1]);
  acc[2] = fmaf(p, __uint_as_float(v.y << 16), acc[2]);
  acc[3] = fmaf(p, __uint_as_float(v.y & 0xffff0000u), acc[3]);
}
template<int DIM>
__device__ inline void gstep2(const char* __restrict__ xlb, int laneB, int s, float p, float* acc){
  uint v = *reinterpret_cast<const uint*>(xlb + (size_t)((uint)s * (uint)(DIM * 2)) + laneB);
  acc[0] = fmaf(p, __uint_as_float(v << 16), acc[0]);
  acc[1] = fmaf(p, __uint_as_float(v & 0xffff0000u), acc[1]);
}

// ---------------- per-node wave gather: softmax + aggregate + bias + LN + ReLU ----------------
template<int H, int DIM, bool BF16_OUT>
__global__ __launch_bounds__(256) void k_aggw(
    const ushort* __restrict__ xl,
    const float* __restrict__ al, const float* __restrict__ ar,
    const int* __restrict__ row_ptr, const int* __restrict__ csr_src,
    const float* __restrict__ bias, const float* __restrict__ gamma, const float* __restrict__ beta,
    float* __restrict__ out, int N)
{
  constexpr int EPL = DIM / 64;        // cols per lane: 4 (DIM=256) or 2 (DIM=128)
  constexpr int PST = 68;              // padded p stride: conflict-free broadcast
  const int tid = (int)threadIdx.x;
  const int wid = tid >> 6, lane = tid & 63;
  __shared__ float plds_all[4][H * PST];
  __shared__ int   slds_all[4][64];
  float* plds = plds_all[wid];
  int*   slds = slds_all[wid];
  const int n = blockIdx.x * 4 + wid;
  if (n >= N) return;
  const int start = __builtin_amdgcn_readfirstlane(row_ptr[n]);
  const int end   = __builtin_amdgcn_readfirstlane(row_ptr[n + 1]);
  const int deg   = end - start;
  const int hm    = (H == 4) ? (lane >> 4) : 0;
  const int hb    = hm * PST;
  const int laneB = lane * (EPL * 2);

  float arv[H];
  #pragma unroll
  for (int h = 0; h < H; h++) arv[h] = ar[(size_t)n * H + h];

  float acc[EPL];
  #pragma unroll
  for (int e = 0; e < EPL; e++) acc[e] = 0.f;
  float psum[H];
  const char* xlb = (const char*)xl;

  auto gather = [&](int cnt){
    int j = 0;
    for (; j + 8 <= cnt; j += 8){
      int s0 = slds[j+0], s1 = slds[j+1], s2 = slds[j+2], s3 = slds[j+3];
      int s4 = slds[j+4], s5 = slds[j+5], s6 = slds[j+6], s7 = slds[j+7];
      float q0 = plds[hb+j+0], q1 = plds[hb+j+1], q2 = plds[hb+j+2], q3 = plds[hb+j+3];
      float q4 = plds[hb+j+4], q5 = plds[hb+j+5], q6 = plds[hb+j+6], q7 = plds[hb+j+7];
      if constexpr (EPL == 4){
        gstep4<DIM>(xlb, laneB, s0, q0, acc); gstep4<DIM>(xlb, laneB, s1, q1, acc);
        gstep4<DIM>(xlb, laneB, s2, q2, acc); gstep4<DIM>(xlb, laneB, s3, q3, acc);
        gstep4<DIM>(xlb, laneB, s4, q4, acc); gstep4<DIM>(xlb, laneB, s5, q5, acc);
        gstep4<DIM>(xlb, laneB, s6, q6, acc); gstep4<DIM>(xlb, laneB, s7, q7, acc);
      } else {
        gstep2<DIM>(xlb, laneB, s0, q0, acc); gstep2<DIM>(xlb, laneB, s1, q1, acc);
        gstep2<DIM>(xlb, laneB, s2, q2, acc); gstep2<DIM>(xlb, laneB, s3, q3, acc);
        gstep2<DIM>(xlb, laneB, s4, q4, acc); gstep2<DIM>(xlb, laneB, s5, q5, acc);
        gstep2<DIM>(xlb, laneB, s6, q6, acc); gstep2<DIM>(xlb, laneB, s7, q7, acc);
      }
    }
    for (; j + 2 <= cnt; j += 2){
      int s0 = slds[j+0], s1 = slds[j+1];
      float q0 = plds[hb+j+0], q1 = plds[hb+j+1];
      if constexpr (EPL == 4){ gstep4<DIM>(xlb, laneB, s0, q0, acc); gstep4<DIM>(xlb, laneB, s1, q1, acc); }
      else                   { gstep2<DIM>(xlb, laneB, s0, q0, acc); gstep2<DIM>(xlb, laneB, s1, q1, acc); }
    }
    if (j < cnt){
      int s0 = slds[j];
      float q0 = plds[hb+j];
      if constexpr (EPL == 4) gstep4<DIM>(xlb, laneB, s0, q0, acc);
      else                    gstep2<DIM>(xlb, laneB, s0, q0, acc);
    }
  };

  if (deg <= 64){
    int src = csr_src[start + (lane < deg ? lane : deg - 1)];
    slds[lane] = src;
    float e[H];
    if constexpr (H == 4){
      float4 a4 = *reinterpret_cast<const float4*>(&al[(size_t)src * 4]);
      e[0] = a4.x + arv[0]; e[1] = a4.y + arv[1]; e[2] = a4.z + arv[2]; e[3] = a4.w + arv[3];
    } else {
      e[0] = al[src] + arv[0];
    }
    #pragma unroll
    for (int h = 0; h < H; h++){
      e[h] = e[h] > 0.f ? e[h] : 0.2f * e[h];
      if (lane >= deg) e[h] = -1e30f;
    }
    float mx[H];
    #pragma unroll
    for (int h = 0; h < H; h++){
      mx[h] = e[h];
      #pragma unroll
      for (int off = 32; off; off >>= 1) mx[h] = fmaxf(mx[h], __shfl_xor(mx[h], off));
    }
    #pragma unroll
    for (int h = 0; h < H; h++){
      float p = (lane < deg) ? __expf(e[h] - mx[h]) : 0.f;
      plds[h * PST + lane] = p;
      psum[h] = p;
      #pragma unroll
      for (int off = 32; off; off >>= 1) psum[h] += __shfl_xor(psum[h], off);
    }
    __asm__ volatile("s_waitcnt lgkmcnt(0)" ::: "memory");
    __builtin_amdgcn_wave_barrier();
    gather(deg);
  } else {
    float mx[H];
    #pragma unroll
    for (int h = 0; h < H; h++) mx[h] = -1e30f;
    for (int i = start + lane; i < end; i += 64){
      int src = csr_src[i];
      if constexpr (H == 4){
        float4 a4 = *reinterpret_cast<const float4*>(&al[(size_t)src * 4]);
        float e0 = a4.x + arv[0]; e0 = e0 > 0.f ? e0 : 0.2f * e0; mx[0] = fmaxf(mx[0], e0);
        float e1 = a4.y + arv[1]; e1 = e1 > 0.f ? e1 : 0.2f * e1; mx[1] = fmaxf(mx[1], e1);
        float e2 = a4.z + arv[2]; e2 = e2 > 0.f ? e2 : 0.2f * e2; mx[2] = fmaxf(mx[2], e2);
        float e3 = a4.w + arv[3]; e3 = e3 > 0.f ? e3 : 0.2f * e3; mx[3] = fmaxf(mx[3], e3);
      } else {
        float e = al[src] + arv[0]; e = e > 0.f ? e : 0.2f * e; mx[0] = fmaxf(mx[0], e);
      }
    }
    #pragma unroll
    for (int h = 0; h < H; h++){
      #pragma unroll
      for (int off = 32; off; off >>= 1) mx[h] = fmaxf(mx[h], __shfl_xor(mx[h], off));
    }
    #pragma unroll
    for (int h = 0; h < H; h++) psum[h] = 0.f;
    for (int c0 = start; c0 < end; c0 += 64){
      const int cnt = min(64, end - c0);
      __asm__ volatile("s_waitcnt lgkmcnt(0)" ::: "memory");
      __builtin_amdgcn_wave_barrier();
      if (lane < cnt){
        int src = csr_src[c0 + lane];
        slds[lane] = src;
        if constexpr (H == 4){
          float4 a4 = *reinterpret_cast<const float4*>(&al[(size_t)src * 4]);
          float e0 = a4.x + arv[0]; e0 = e0 > 0.f ? e0 : 0.2f * e0; float p0 = __expf(e0 - mx[0]);
          float e1 = a4.y + arv[1]; e1 = e1 > 0.f ? e1 : 0.2f * e1; float p1 = __expf(e1 - mx[1]);
          float e2 = a4.z + arv[2]; e2 = e2 > 0.f ? e2 : 0.2f * e2; float p2 = __expf(e2 - mx[2]);
          float e3 = a4.w + arv[3]; e3 = e3 > 0.f ? e3 : 0.2f * e3; float p3 = __expf(e3 - mx[3]);
          plds[0 * PST + lane] = p0; plds[1 * PST + lane] = p1;
          plds[2 * PST + lane] = p2; plds[3 * PST + lane] = p3;
          psum[0] += p0; psum[1] += p1; psum[2] += p2; psum[3] += p3;
        } else {
          float e = al[src] + arv[0]; e = e > 0.f ? e : 0.2f * e; float p = __expf(e - mx[0]);
          plds[lane] = p; psum[0] += p;
        }
      }
      __asm__ volatile("s_waitcnt lgkmcnt(0)" ::: "memory");
      __builtin_amdgcn_wave_barrier();
      gather(cnt);
    }
    #pragma unroll
    for (int h = 0; h < H; h++){
      #pragma unroll
      for (int off = 32; off; off >>= 1) psum[h] += __shfl_xor(psum[h], off);
    }
  }

  float ssel;
  if constexpr (H == 4){
    ssel = (hm == 0) ? psum[0] : (hm == 1) ? psum[1] : (hm == 2) ? psum[2] : psum[3];
  } else {
    ssel = psum[0];
  }
  const float inv = 1.f / (ssel + 1e-16f);

  float v[EPL];
  if constexpr (EPL == 4){
    float4 bb = *reinterpret_cast<const float4*>(&bias[lane * 4]);
    v[0] = fmaf(acc[0], inv, bb.x); v[1] = fmaf(acc[1], inv, bb.y);
    v[2] = fmaf(acc[2], inv, bb.z); v[3] = fmaf(acc[3], inv, bb.w);
  } else {
    float2 bb = *reinterpret_cast<const float2*>(&bias[lane * 2]);
    v[0] = fmaf(acc[0], inv, bb.x); v[1] = fmaf(acc[1], inv, bb.y);
  }
  float s1 = 0.f, s2 = 0.f;
  #pragma unroll
  for (int e = 0; e < EPL; e++){ s1 += v[e]; s2 += v[e] * v[e]; }
  #pragma unroll
  for (int off = 32; off; off >>= 1){ s1 += __shfl_xor(s1, off); s2 += __shfl_xor(s2, off); }
  const float mu = s1 / DIM;
  const float rstd = rsqrtf(s2 / DIM - mu * mu + EPS_LN);

  if constexpr (EPL == 4){
    float4 gg = *reinterpret_cast<const float4*>(&gamma[lane * 4]);
    float4 be = *reinterpret_cast<const float4*>(&beta[lane * 4]);
    float o0 = fmaxf((v[0] - mu) * rstd * gg.x + be.x, 0.f);
    float o1 = fmaxf((v[1] - mu) * rstd * gg.y + be.y, 0.f);
    float o2 = fmaxf((v[2] - mu) * rstd * gg.z + be.z, 0.f);
    float o3 = fmaxf((v[3] - mu) * rstd * gg.w + be.w, 0.f);
    if constexpr (BF16_OUT){
      uint2 pk;
      pk.x = (uint)f2bf(o0) | ((uint)f2bf(o1) << 16);
      pk.y = (uint)f2bf(o2) | ((uint)f2bf(o3) << 16);
      *reinterpret_cast<uint2*>(&reinterpret_cast<ushort*>(out)[(size_t)n * DIM + lane * 4]) = pk;
    } else {
      *reinterpret_cast<float4*>(&out[(size_t)n * DIM + lane * 4]) = make_float4(o0, o1, o2, o3);
    }
  } else {
    float2 gg = *reinterpret_cast<const float2*>(&gamma[lane * 2]);
    float2 be = *reinterpret_cast<const float2*>(&beta[lane * 2]);
    float o0 = fmaxf((v[0] - mu) * rstd * gg.x + be.x, 0.f);
    float o1 = fmaxf((v[1] - mu) * rstd * gg.y + be.y, 0.f);
    if constexpr (BF16_OUT){
      uint pk = (uint)f2bf(o0) | ((uint)f2bf(o1) << 16);
      reinterpret_cast<uint*>(out)[(size_t)n * (DIM / 2) + lane] = pk;
    } else {
      *reinterpret_cast<float2*>(&out[(size_t)n * DIM + lane * 2]) = make_float2(o0, o1);
    }
  }
}

// ---------------- parallel pooling: Q chunks/graph, float4 lanes, no fences ----------------
__global__ __launch_bounds__(256) void k_pool(const float* __restrict__ h, const int* __restrict__ pos,
    float* __restrict__ pool_sum, uint* __restrict__ pool_max){
  const int t = (int)threadIdx.x;
  const int g = blockIdx.x / POOL_Q;
  const int q = blockIdx.x % POOL_Q;
  const int s = pos[g], e = pos[g + 1];
  const int len = e - s;
  if (len <= 0) return;
  const int chunk = (len + POOL_Q - 1) / POOL_Q;
  const int n0 = s + q * chunk;
  const int n1 = min(n0 + chunk, e);
  if (n0 >= n1) return;
  const int qd = t & 31;
  const int slot = t >> 5;
  const int wid = t >> 6;

  float4 sum = make_float4(0.f, 0.f, 0.f, 0.f);
  float4 mx  = make_float4(0.f, 0.f, 0.f, 0.f);
  for (int n = n0 + slot; n < n1; n += 8){
    float4 v = *reinterpret_cast<const float4*>(&h[(size_t)n * 128 + qd * 4]);
    sum.x += v.x; sum.y += v.y; sum.z += v.z; sum.w += v.w;
    mx.x = fmaxf(mx.x, v.x); mx.y = fmaxf(mx.y, v.y);
    mx.z = fmaxf(mx.z, v.z); mx.w = fmaxf(mx.w, v.w);
  }
  sum.x += __shfl_xor(sum.x, 32); sum.y += __shfl_xor(sum.y, 32);
  sum.z += __shfl_xor(sum.z, 32); sum.w += __shfl_xor(sum.w, 32);
  mx.x = fmaxf(mx.x, __shfl_xor(mx.x, 32)); mx.y = fmaxf(mx.y, __shfl_xor(mx.y, 32));
  mx.z = fmaxf(mx.z, __shfl_xor(mx.z, 32)); mx.w = fmaxf(mx.w, __shfl_xor(mx.w, 32));
  __shared__ float4 lsum[4][32], lmax[4][32];
  if ((t & 63) < 32){ lsum[wid][qd] = sum; lmax[wid][qd] = mx; }
  __syncthreads();
  if (t < 32){
    float4 S = lsum[0][t], M = lmax[0][t];
    #pragma unroll
    for (int w = 1; w < 4; w++){
      float4 S2 = lsum[w][t], M2 = lmax[w][t];
      S.x += S2.x; S.y += S2.y; S.z += S2.z; S.w += S2.w;
      M.x = fmaxf(M.x, M2.x); M.y = fmaxf(M.y, M2.y);
      M.z = fmaxf(M.z, M2.z); M.w = fmaxf(M.w, M2.w);
    }
    float* ps = &pool_sum[g * 128 + t * 4];
    uint*  pm = &pool_max[g * 128 + t * 4];
    atomicAdd(&ps[0], S.x); atomicAdd(&ps[1], S.y);
    atomicAdd(&ps[2], S.z); atomicAdd(&ps[3], S.w);
    atomicMax(&pm[0], __float_as_uint(M.x)); atomicMax(&pm[1], __float_as_uint(M.y));
    atomicMax(&pm[2], __float_as_uint(M.z)); atomicMax(&pm[3], __float_as_uint(M.w));
  }
}

// ---------------- final projection ----------------
__global__ __launch_bounds__(128) void k_final(const float* __restrict__ pool_sum,
    const uint* __restrict__ pool_max, const int* __restrict__ pos,
    const float* __restrict__ Wp, const float* __restrict__ bp, float* __restrict__ out){
  const int g = blockIdx.x;
  const int j = (int)threadIdx.x;
  float inv = 1.f / fmaxf((float)(pos[g + 1] - pos[g]), 1.f);
  float acc = bp[j];
  #pragma unroll 4
  for (int k = 0; k < 128; k++)
    acc = fmaf(pool_sum[g * 128 + k] * inv, Wp[k * 128 + j], acc);
  #pragma unroll 4
  for (int k = 0; k < 128; k++)
    acc = fmaf(__uint_as_float(pool_max[g * 128 + k]), Wp[(128 + k) * 128 + j], acc);
  out[g * 128 + j] = acc;
}

// ---------------- launch ----------------
extern "C" void kernel_launch(void* const* d_in, const int* in_sizes, int n_in,
                              void* d_out, int out_size, void* d_ws, size_t ws_size,
                              hipStream_t stream){
  const float* x     = (const float*)d_in[0];
  const int*   ei    = (const int*)d_in[1];
  const int*   batch = (const int*)d_in[2];
  const float* W1    = (const float*)d_in[3];
  const float* asrc1 = (const float*)d_in[4];
  const float* adst1 = (const float*)d_in[5];
  const float* b1    = (const float*)d_in[6];
  const float* g1    = (const float*)d_in[7];
  const float* be1   = (const float*)d_in[8];
  const float* W2    = (const float*)d_in[9];
  const float* asrc2 = (const float*)d_in[10];
  const float* adst2 = (const float*)d_in[11];
  const float* b2    = (const float*)d_in[12];
  const float* g2    = (const float*)d_in[13];
  const float* be2   = (const float*)d_in[14];
  const float* W3    = (const float*)d_in[15];
  const float* asrc3 = (const float*)d_in[16];
  const float* adst3 = (const float*)d_in[17];
  const float* b3    = (const float*)d_in[18];
  const float* g3    = (const float*)d_in[19];
  const float* be3   = (const float*)d_in[20];
  const float* Wp    = (const float*)d_in[21];
  const float* bp    = (const float*)d_in[22];

  const int N = in_sizes[0] / 128;
  const int E = in_sizes[1] / 2;
  const int G = out_size / 128;
  const int EN = E + N;

  char* ws = (char*)d_ws;
  size_t off = 0;
  auto alloc = [&](size_t bytes) -> char* {
    char* p = ws + off;
    off = (off + bytes + 255) & ~(size_t)255;
    return p;
  };
  ushort*   region0  = (ushort*)alloc((size_t)N * 256 * 2);
  ushort*   x_bf     = region0;
  ushort*   h_bf     = region0;
  ushort*   xbufA    = (ushort*)alloc((size_t)N * 256 * 2);  // xl (bf16)
  float*    xbufB    = (float*)alloc((size_t)N * 128 * 4);   // layer-3 output (f32, pooling)
  float*    al       = (float*)alloc((size_t)N * 4 * 4);
  float*    ar       = (float*)alloc((size_t)N * 4 * 4);
  int*      deg      = (int*)alloc((size_t)N * 4);
  int*      row_ptr  = (int*)alloc((size_t)(N + 1) * 4);
  int*      cursor   = (int*)alloc((size_t)N * 4);
  int*      csr_src  = (int*)alloc((size_t)EN * 4);
  int*      pos      = (int*)alloc((size_t)(G + 1) * 4);
  float*    pool_sum = (float*)alloc((size_t)G * 128 * 4);
  uint*     pool_max = (uint*)alloc((size_t)G * 128 * 4);
  ushort*   W1t      = (ushort*)alloc((size_t)256 * 128 * 2);
  ushort*   W2t      = (ushort*)alloc((size_t)256 * 256 * 2);
  ushort*   W3t      = (ushort*)alloc((size_t)128 * 256 * 2);
  const int NB = (N + 1023) / 1024;
  int*      pref     = (int*)alloc((size_t)NB * 4);
  int*      flag     = (int*)alloc((size_t)NB * 4);

  hipMemsetAsync(deg, 0, (size_t)N * 4, stream);

  // mega-prep (cast/transpose/deg/bounds/pool-zero/flag) -> lookback scan -> scatter
  {
    int total = N * 32 + 256 * 128 + 256 * 256 + 128 * 256 + EN + G * 128;
    k_prep<<<(total + 255) / 256, 256, 0, stream>>>(x, x_bf, W1, W1t, W2, W2t, W3, W3t,
                                                    ei, deg, batch, pos,
                                                    pool_sum, pool_max, flag, N, E, G, NB);
  }
  k_scanall<<<NB, 1024, 0, stream>>>(deg, row_ptr, cursor, pref, flag, N);
  k_scatter<<<(EN + 255) / 256, 256, 0, stream>>>(ei, cursor, csr_src, E, N);

  const int MB = (N + 127) / 128;
  const int NB4 = (N + 3) / 4;

  // Layer 1: 128 -> 256, H=4, C=64
  k_mm<128, 256, 4><<<dim3(MB, 2), 256, 0, stream>>>(x_bf, W1t, xbufA, asrc1, adst1, al, ar, N);
  k_aggw<4, 256, true><<<NB4, 256, 0, stream>>>(xbufA, al, ar, row_ptr, csr_src, b1, g1, be1, (float*)h_bf, N);

  // Layer 2: 256 -> 256, H=4, C=64
  k_mm<256, 256, 4><<<dim3(MB, 2), 256, 0, stream>>>(h_bf, W2t, xbufA, asrc2, adst2, al, ar, N);
  k_aggw<4, 256, true><<<NB4, 256, 0, stream>>>(xbufA, al, ar, row_ptr, csr_src, b2, g2, be2, (float*)h_bf, N);

  // Layer 3: 256 -> 128, H=1, C=128
  k_mm<256, 128, 1><<<dim3(MB, 1), 256, 0, stream>>>(h_bf, W3t, xbufA, asrc3, adst3, al, ar, N);
  k_aggw<1, 128, false><<<NB4, 256, 0, stream>>>(xbufA, al, ar, row_ptr, csr_src, b3, g3, be3, xbufB, N);

  // Pooling + final projection
  k_pool<<<G * POOL_Q, 256, 0, stream>>>(xbufB, pos, pool_sum, pool_max);
  k_final<<<G, 128, 0, stream>>>(pool_sum, pool_max, pos, Wp, bp, (float*)d_out);
}

// Round 16
// 379.752 us; speedup vs baseline: 1.1246x; 1.1246x over previous
//
#include <hip/hip_runtime.h>

#define EPS_LN 1e-5f
typedef unsigned int uint;

using bf16x8 = __attribute__((ext_vector_type(8))) short;
using f32x4  = __attribute__((ext_vector_type(4))) float;

__device__ inline float bf2f(ushort h){ return __uint_as_float(((uint)h) << 16); }
__device__ inline ushort f2bf(float f){
  uint u = __float_as_uint(f);
  u += 0x7fffu + ((u >> 16) & 1u);   // round-to-nearest-even
  return (ushort)(u >> 16);
}

__device__ inline void gload_lds16(const ushort* g, ushort* l){
  __builtin_amdgcn_global_load_lds(
      (const __attribute__((address_space(1))) uint*)g,
      (__attribute__((address_space(3))) uint*)l, 16, 0, 0);
}

#define POOL_Q 32   // chunks per graph in k_pool

// ---------------- CSR build (dst-indexed) ----------------
__global__ void k_deg(const int* __restrict__ ei, int* __restrict__ deg, int E, int N){
  int e = blockIdx.x * 256 + threadIdx.x;
  if (e >= E + N) return;
  int dst = (e < E) ? ei[E + e] : (e - E);   // self loops appended
  atomicAdd(&deg[dst], 1);
}

__global__ __launch_bounds__(1024) void k_bsum(const int* __restrict__ deg, int* __restrict__ bsum, int n){
  __shared__ int ws[16];
  const int t = (int)threadIdx.x, lane = t & 63, w = t >> 6;
  int i = blockIdx.x * 1024 + t;
  int v = (i < n) ? deg[i] : 0;
  #pragma unroll
  for (int off = 32; off; off >>= 1) v += __shfl_xor(v, off);
  if (lane == 0) ws[w] = v;
  __syncthreads();
  if (t == 0){
    int s = 0;
    #pragma unroll
    for (int k = 0; k < 16; k++) s += ws[k];
    bsum[blockIdx.x] = s;
  }
}

// block 0: scan of block sums; block 1: graph bounds; blocks 2+: zero pool buffers
__global__ __launch_bounds__(256) void k_misc(int* __restrict__ bsum, int nb,
                                              const int* __restrict__ batch, int* __restrict__ pos,
                                              float* __restrict__ pool_sum, uint* __restrict__ pool_max,
                                              int N, int G){
  const int t = (int)threadIdx.x;
  const int b = (int)blockIdx.x;
  if (b == 0){
    if (t >= 64) return;
    const int lane = t;
    int carry = 0;
    for (int b0 = 0; b0 < nb; b0 += 64){
      int i = b0 + lane;
      int v = (i < nb) ? bsum[i] : 0;
      int s = v;
      #pragma unroll
      for (int off = 1; off < 64; off <<= 1){ int u = __shfl_up(s, off); if (lane >= off) s += u; }
      if (i < nb) bsum[i] = s - v + carry;   // exclusive
      carry += __shfl(s, 63);
    }
  } else if (b == 1){
    int g = t;
    if (g > G) return;
    int lo = 0, hi = N;
    while (lo < hi){
      int mid = (lo + hi) >> 1;
      if (batch[mid] < g) lo = mid + 1; else hi = mid;
    }
    pos[g] = lo;
  } else {
    int i = (b - 2) * 256 + t;
    if (i < G * 128){ pool_sum[i] = 0.f; pool_max[i] = 0u; }
  }
}

__global__ __launch_bounds__(1024) void k_scan2(const int* __restrict__ deg, const int* __restrict__ bpre,
                                                int* __restrict__ row_ptr, int* __restrict__ cursor, int n){
  __shared__ int wsum[16];
  const int t = (int)threadIdx.x, lane = t & 63, w = t >> 6;
  int i = blockIdx.x * 1024 + t;
  int v = (i < n) ? deg[i] : 0;
  int s = v;
  #pragma unroll
  for (int off = 1; off < 64; off <<= 1){ int u = __shfl_up(s, off); if (lane >= off) s += u; }
  if (lane == 63) wsum[w] = s;
  __syncthreads();
  if (w == 0 && lane < 16){
    int sc = wsum[lane];
    #pragma unroll
    for (int off = 1; off < 16; off <<= 1){ int u = __shfl_up(sc, off); if (lane >= off) sc += u; }
    wsum[lane] = sc;
  }
  __syncthreads();
  int prefix = bpre[blockIdx.x] + (w ? wsum[w - 1] : 0) + s;   // inclusive
  if (i < n){ row_ptr[i + 1] = prefix; cursor[i] = prefix - v; }
  if (i == 0) row_ptr[0] = 0;
}

__global__ void k_scatter(const int* __restrict__ ei, int* __restrict__ cursor,
                          int* __restrict__ csr_src, int E, int N){
  int e = blockIdx.x * 256 + threadIdx.x;
  if (e >= E + N) return;
  int src, dst;
  if (e < E){ src = ei[e]; dst = ei[E + e]; } else { src = dst = e - E; }
  int pos = atomicAdd(&cursor[dst], 1);
  csr_src[pos] = src;
}

// ---------------- combined dtype prep: cast x + transpose/cast 3 weights ----------------
__global__ void k_prep(const float* __restrict__ x, ushort* __restrict__ x_bf,
                       const float* __restrict__ W1, ushort* __restrict__ W1t,
                       const float* __restrict__ W2, ushort* __restrict__ W2t,
                       const float* __restrict__ W3, ushort* __restrict__ W3t, int N){
  int i = blockIdx.x * 256 + threadIdx.x;
  const int c0 = N * 32;                    // float4 quads of x
  if (i < c0){
    float4 v = reinterpret_cast<const float4*>(x)[i];
    ushort4 o; o.x = f2bf(v.x); o.y = f2bf(v.y); o.z = f2bf(v.z); o.w = f2bf(v.w);
    reinterpret_cast<ushort4*>(x_bf)[i] = o;
    return;
  }
  i -= c0;
  if (i < 256 * 128){                       // W1t[n*128+k] = W1[k*256+n]
    int n = i >> 7, k = i & 127;
    W1t[i] = f2bf(W1[(size_t)k * 256 + n]);
    return;
  }
  i -= 256 * 128;
  if (i < 256 * 256){                       // W2t[n*256+k] = W2[k*256+n]
    int n = i >> 8, k = i & 255;
    W2t[i] = f2bf(W2[(size_t)k * 256 + n]);
    return;
  }
  i -= 256 * 256;
  if (i < 128 * 256){                       // W3t[n*256+k] = W3[k*128+n]
    int n = i >> 8, k = i & 255;
    W3t[i] = f2bf(W3[(size_t)k * 128 + n]);
  }
}

// ---------------- MFMA GEMM (BK=64, global_load_lds staging) + fused attn-coef epilogue ----
template<int K, int N, int H>
__global__ __launch_bounds__(256, 4) void k_mm(const ushort* __restrict__ A,
                                               const ushort* __restrict__ Wt,
                                               ushort* __restrict__ out,
                                               const float* __restrict__ asrc,
                                               const float* __restrict__ adst,
                                               float* __restrict__ al, float* __restrict__ ar,
                                               int M)
{
  constexpr int BANDS = (N / H) / 64;   // 64-col bands per head: 1 (H=4,N=256) or 2 (H=1,N=128)
  __shared__ __align__(16) ushort ldsA[128 * 64];
  __shared__ __align__(16) ushort ldsB[128 * 64];

  const int t = (int)threadIdx.x;
  const int lane = t & 63;
  const int w = t >> 6;
  const int wm = w >> 1, wn = w & 1;
  const int row0 = blockIdx.x * 128;
  const int n0 = blockIdx.y * 128;
  const int growR = w * 8 + (lane >> 3);     // row-in-round 0..31
  const int gcolA = (lane & 7) * 8;          // col elems 0..56

  f32x4 acc[4][4];
  #pragma unroll
  for (int mt = 0; mt < 4; mt++)
    #pragma unroll
    for (int nt = 0; nt < 4; nt++)
      acc[mt][nt] = (f32x4){0.f, 0.f, 0.f, 0.f};

  #pragma unroll
  for (int kt = 0; kt < K / 64; kt++){
    if (kt) __syncthreads();                 // all ds_reads of prev tile drained
    #pragma unroll
    for (int r = 0; r < 4; r++){
      int ga = row0 + r * 32 + growR; if (ga > M - 1) ga = M - 1;
      int gb = n0 + r * 32 + growR;          // N dims exact multiples of 128
      gload_lds16(&A [(size_t)ga * K + kt * 64 + gcolA], ldsA + r * 2048 + w * 512);
      gload_lds16(&Wt[(size_t)gb * K + kt * 64 + gcolA], ldsB + r * 2048 + w * 512);
    }
    __syncthreads();                         // vmcnt(0) drained by barrier semantics

    #pragma unroll
    for (int ks = 0; ks < 2; ks++){
      bf16x8 af[4], bfr[4];
      const int kb8 = ks * 4 + (lane >> 4);  // 0..7
      #pragma unroll
      for (int mt = 0; mt < 4; mt++){
        int arow = wm * 64 + mt * 16 + (lane & 15);
        af[mt]  = *reinterpret_cast<const bf16x8*>(&ldsA[arow * 64 + kb8 * 8]);
        int brow = wn * 64 + mt * 16 + (lane & 15);
        bfr[mt] = *reinterpret_cast<const bf16x8*>(&ldsB[brow * 64 + kb8 * 8]);
      }
      #pragma unroll
      for (int mt = 0; mt < 4; mt++)
        #pragma unroll
        for (int nt = 0; nt < 4; nt++)
          acc[mt][nt] = __builtin_amdgcn_mfma_f32_16x16x32_bf16(af[mt], bfr[nt], acc[mt][nt], 0, 0, 0);
    }
  }

  // ---- epilogue 1: C store (C/D map col=lane&15, row=(lane>>4)*4+r, m89-verified) ----
  #pragma unroll
  for (int mt = 0; mt < 4; mt++){
    const int grow_b = row0 + wm * 64 + mt * 16 + (lane >> 4) * 4;
    #pragma unroll
    for (int nt = 0; nt < 4; nt++){
      const int gcol = n0 + wn * 64 + nt * 16 + (lane & 15);
      #pragma unroll
      for (int r = 0; r < 4; r++){
        int grow = grow_b + r;
        if (grow < M) out[(size_t)grow * N + gcol] = f2bf(acc[mt][nt][r]);
      }
    }
  }

  // ---- epilogue 2: fused attention coefficients from f32 accumulators ----
  float av[4], bv[4];
  #pragma unroll
  for (int nt = 0; nt < 4; nt++){
    int col = n0 + wn * 64 + nt * 16 + (lane & 15);
    av[nt] = asrc[col]; bv[nt] = adst[col];
  }
  float paA[4][4], pbA[4][4];     // [mt][r], reduced over the 64-col band
  #pragma unroll
  for (int mt = 0; mt < 4; mt++){
    #pragma unroll
    for (int r = 0; r < 4; r++){
      float pa = acc[mt][0][r] * av[0] + acc[mt][1][r] * av[1]
               + acc[mt][2][r] * av[2] + acc[mt][3][r] * av[3];
      float pb = acc[mt][0][r] * bv[0] + acc[mt][1][r] * bv[1]
               + acc[mt][2][r] * bv[2] + acc[mt][3][r] * bv[3];
      #pragma unroll
      for (int off = 1; off < 16; off <<= 1){ pa += __shfl_xor(pa, off); pb += __shfl_xor(pb, off); }
      paA[mt][r] = pa; pbA[mt][r] = pb;
    }
  }
  if constexpr (BANDS == 1){
    const int h = (n0 + wn * 64) / (N / H);
    if ((lane & 15) == 0){
      #pragma unroll
      for (int mt = 0; mt < 4; mt++){
        #pragma unroll
        for (int r = 0; r < 4; r++){
          int row = row0 + wm * 64 + mt * 16 + (lane >> 4) * 4 + r;
          if (row < M){
            al[(size_t)row * H + h] = paA[mt][r];
            ar[(size_t)row * H + h] = pbA[mt][r];
          }
        }
      }
    }
  } else {
    // H=1: two column bands (wn=0,1) sum into the same head; combine via LDS
    __syncthreads();                          // ldsA free for reuse
    float* fl = reinterpret_cast<float*>(ldsA);   // 256 floats
    if (wn == 0 && (lane & 15) == 0){
      #pragma unroll
      for (int mt = 0; mt < 4; mt++){
        #pragma unroll
        for (int r = 0; r < 4; r++){
          int rl = wm * 64 + mt * 16 + (lane >> 4) * 4 + r;
          fl[rl] = paA[mt][r]; fl[128 + rl] = pbA[mt][r];
        }
      }
    }
    __syncthreads();
    if (wn == 1 && (lane & 15) == 0){
      #pragma unroll
      for (int mt = 0; mt < 4; mt++){
        #pragma unroll
        for (int r = 0; r < 4; r++){
          int rl = wm * 64 + mt * 16 + (lane >> 4) * 4 + r;
          int row = row0 + rl;
          if (row < M){
            al[row] = fl[rl] + paA[mt][r];
            ar[row] = fl[128 + rl] + pbA[mt][r];
          }
        }
      }
    }
  }
}

// ---- gather helpers: one edge row contribution ----
template<int DIM>
__device__ inline void gstep4(const char* __restrict__ xlb, int laneB, int s, float p, float* acc){
  uint2 v = *reinterpret_cast<const uint2*>(xlb + (size_t)((uint)s * (uint)(DIM * 2)) + laneB);
  acc[0] = fmaf(p, __uint_as_float(v.x << 16), acc[0]);
  acc[1] = fmaf(p, __uint_as_float(v.x & 0xffff0000u), acc[1]);
  acc[2] = fmaf(p, __uint_as_float(v.y << 16), acc[2]);
  acc[3] = fmaf(p, __uint_as_float(v.y & 0xffff0000u), acc[3]);
}
template<int DIM>
__device__ inline void gstep2(const char* __restrict__ xlb, int laneB, int s, float p, float* acc){
  uint v = *reinterpret_cast<const uint*>(xlb + (size_t)((uint)s * (uint)(DIM * 2)) + laneB);
  acc[0] = fmaf(p, __uint_as_float(v << 16), acc[0]);
  acc[1] = fmaf(p, __uint_as_float(v & 0xffff0000u), acc[1]);
}

// ---------------- per-node wave gather: softmax + aggregate + bias + LN + ReLU ----------------
template<int H, int DIM, bool BF16_OUT>
__global__ __launch_bounds__(256) void k_aggw(
    const ushort* __restrict__ xl,
    const float* __restrict__ al, const float* __restrict__ ar,
    const int* __restrict__ row_ptr, const int* __restrict__ csr_src,
    const float* __restrict__ bias, const float* __restrict__ gamma, const float* __restrict__ beta,
    float* __restrict__ out, int N)
{
  constexpr int EPL = DIM / 64;        // cols per lane: 4 (DIM=256) or 2 (DIM=128)
  constexpr int PST = 68;              // padded p stride: conflict-free broadcast
  const int tid = (int)threadIdx.x;
  const int wid = tid >> 6, lane = tid & 63;
  __shared__ float plds_all[4][H * PST];
  __shared__ int   slds_all[4][64];
  float* plds = plds_all[wid];
  int*   slds = slds_all[wid];
  const int n = blockIdx.x * 4 + wid;
  if (n >= N) return;
  const int start = __builtin_amdgcn_readfirstlane(row_ptr[n]);
  const int end   = __builtin_amdgcn_readfirstlane(row_ptr[n + 1]);
  const int deg   = end - start;
  const int hm    = (H == 4) ? (lane >> 4) : 0;
  const int hb    = hm * PST;
  const int laneB = lane * (EPL * 2);

  float arv[H];
  #pragma unroll
  for (int h = 0; h < H; h++) arv[h] = ar[(size_t)n * H + h];

  float acc[EPL];
  #pragma unroll
  for (int e = 0; e < EPL; e++) acc[e] = 0.f;
  float psum[H];
  const char* xlb = (const char*)xl;

  auto gather = [&](int cnt){
    int j = 0;
    for (; j + 8 <= cnt; j += 8){
      int s0 = slds[j+0], s1 = slds[j+1], s2 = slds[j+2], s3 = slds[j+3];
      int s4 = slds[j+4], s5 = slds[j+5], s6 = slds[j+6], s7 = slds[j+7];
      float q0 = plds[hb+j+0], q1 = plds[hb+j+1], q2 = plds[hb+j+2], q3 = plds[hb+j+3];
      float q4 = plds[hb+j+4], q5 = plds[hb+j+5], q6 = plds[hb+j+6], q7 = plds[hb+j+7];
      if constexpr (EPL == 4){
        gstep4<DIM>(xlb, laneB, s0, q0, acc); gstep4<DIM>(xlb, laneB, s1, q1, acc);
        gstep4<DIM>(xlb, laneB, s2, q2, acc); gstep4<DIM>(xlb, laneB, s3, q3, acc);
        gstep4<DIM>(xlb, laneB, s4, q4, acc); gstep4<DIM>(xlb, laneB, s5, q5, acc);
        gstep4<DIM>(xlb, laneB, s6, q6, acc); gstep4<DIM>(xlb, laneB, s7, q7, acc);
      } else {
        gstep2<DIM>(xlb, laneB, s0, q0, acc); gstep2<DIM>(xlb, laneB, s1, q1, acc);
        gstep2<DIM>(xlb, laneB, s2, q2, acc); gstep2<DIM>(xlb, laneB, s3, q3, acc);
        gstep2<DIM>(xlb, laneB, s4, q4, acc); gstep2<DIM>(xlb, laneB, s5, q5, acc);
        gstep2<DIM>(xlb, laneB, s6, q6, acc); gstep2<DIM>(xlb, laneB, s7, q7, acc);
      }
    }
    for (; j + 2 <= cnt; j += 2){
      int s0 = slds[j+0], s1 = slds[j+1];
      float q0 = plds[hb+j+0], q1 = plds[hb+j+1];
      if constexpr (EPL == 4){ gstep4<DIM>(xlb, laneB, s0, q0, acc); gstep4<DIM>(xlb, laneB, s1, q1, acc); }
      else                   { gstep2<DIM>(xlb, laneB, s0, q0, acc); gstep2<DIM>(xlb, laneB, s1, q1, acc); }
    }
    if (j < cnt){
      int s0 = slds[j];
      float q0 = plds[hb+j];
      if constexpr (EPL == 4) gstep4<DIM>(xlb, laneB, s0, q0, acc);
      else                    gstep2<DIM>(xlb, laneB, s0, q0, acc);
    }
  };

  if (deg <= 64){
    int src = csr_src[start + (lane < deg ? lane : deg - 1)];
    slds[lane] = src;
    float e[H];
    if constexpr (H == 4){
      float4 a4 = *reinterpret_cast<const float4*>(&al[(size_t)src * 4]);
      e[0] = a4.x + arv[0]; e[1] = a4.y + arv[1]; e[2] = a4.z + arv[2]; e[3] = a4.w + arv[3];
    } else {
      e[0] = al[src] + arv[0];
    }
    #pragma unroll
    for (int h = 0; h < H; h++){
      e[h] = e[h] > 0.f ? e[h] : 0.2f * e[h];
      if (lane >= deg) e[h] = -1e30f;
    }
    float mx[H];
    #pragma unroll
    for (int h = 0; h < H; h++){
      mx[h] = e[h];
      #pragma unroll
      for (int off = 32; off; off >>= 1) mx[h] = fmaxf(mx[h], __shfl_xor(mx[h], off));
    }
    #pragma unroll
    for (int h = 0; h < H; h++){
      float p = (lane < deg) ? __expf(e[h] - mx[h]) : 0.f;
      plds[h * PST + lane] = p;
      psum[h] = p;
      #pragma unroll
      for (int off = 32; off; off >>= 1) psum[h] += __shfl_xor(psum[h], off);
    }
    __asm__ volatile("s_waitcnt lgkmcnt(0)" ::: "memory");
    __builtin_amdgcn_wave_barrier();
    gather(deg);
  } else {
    float mx[H];
    #pragma unroll
    for (int h = 0; h < H; h++) mx[h] = -1e30f;
    for (int i = start + lane; i < end; i += 64){
      int src = csr_src[i];
      if constexpr (H == 4){
        float4 a4 = *reinterpret_cast<const float4*>(&al[(size_t)src * 4]);
        float e0 = a4.x + arv[0]; e0 = e0 > 0.f ? e0 : 0.2f * e0; mx[0] = fmaxf(mx[0], e0);
        float e1 = a4.y + arv[1]; e1 = e1 > 0.f ? e1 : 0.2f * e1; mx[1] = fmaxf(mx[1], e1);
        float e2 = a4.z + arv[2]; e2 = e2 > 0.f ? e2 : 0.2f * e2; mx[2] = fmaxf(mx[2], e2);
        float e3 = a4.w + arv[3]; e3 = e3 > 0.f ? e3 : 0.2f * e3; mx[3] = fmaxf(mx[3], e3);
      } else {
        float e = al[src] + arv[0]; e = e > 0.f ? e : 0.2f * e; mx[0] = fmaxf(mx[0], e);
      }
    }
    #pragma unroll
    for (int h = 0; h < H; h++){
      #pragma unroll
      for (int off = 32; off; off >>= 1) mx[h] = fmaxf(mx[h], __shfl_xor(mx[h], off));
    }
    #pragma unroll
    for (int h = 0; h < H; h++) psum[h] = 0.f;
    for (int c0 = start; c0 < end; c0 += 64){
      const int cnt = min(64, end - c0);
      __asm__ volatile("s_waitcnt lgkmcnt(0)" ::: "memory");
      __builtin_amdgcn_wave_barrier();
      if (lane < cnt){
        int src = csr_src[c0 + lane];
        slds[lane] = src;
        if constexpr (H == 4){
          float4 a4 = *reinterpret_cast<const float4*>(&al[(size_t)src * 4]);
          float e0 = a4.x + arv[0]; e0 = e0 > 0.f ? e0 : 0.2f * e0; float p0 = __expf(e0 - mx[0]);
          float e1 = a4.y + arv[1]; e1 = e1 > 0.f ? e1 : 0.2f * e1; float p1 = __expf(e1 - mx[1]);
          float e2 = a4.z + arv[2]; e2 = e2 > 0.f ? e2 : 0.2f * e2; float p2 = __expf(e2 - mx[2]);
          float e3 = a4.w + arv[3]; e3 = e3 > 0.f ? e3 : 0.2f * e3; float p3 = __expf(e3 - mx[3]);
          plds[0 * PST + lane] = p0; plds[1 * PST + lane] = p1;
          plds[2 * PST + lane] = p2; plds[3 * PST + lane] = p3;
          psum[0] += p0; psum[1] += p1; psum[2] += p2; psum[3] += p3;
        } else {
          float e = al[src] + arv[0]; e = e > 0.f ? e : 0.2f * e; float p = __expf(e - mx[0]);
          plds[lane] = p; psum[0] += p;
        }
      }
      __asm__ volatile("s_waitcnt lgkmcnt(0)" ::: "memory");
      __builtin_amdgcn_wave_barrier();
      gather(cnt);
    }
    #pragma unroll
    for (int h = 0; h < H; h++){
      #pragma unroll
      for (int off = 32; off; off >>= 1) psum[h] += __shfl_xor(psum[h], off);
    }
  }

  float ssel;
  if constexpr (H == 4){
    ssel = (hm == 0) ? psum[0] : (hm == 1) ? psum[1] : (hm == 2) ? psum[2] : psum[3];
  } else {
    ssel = psum[0];
  }
  const float inv = 1.f / (ssel + 1e-16f);

  float v[EPL];
  if constexpr (EPL == 4){
    float4 bb = *reinterpret_cast<const float4*>(&bias[lane * 4]);
    v[0] = fmaf(acc[0], inv, bb.x); v[1] = fmaf(acc[1], inv, bb.y);
    v[2] = fmaf(acc[2], inv, bb.z); v[3] = fmaf(acc[3], inv, bb.w);
  } else {
    float2 bb = *reinterpret_cast<const float2*>(&bias[lane * 2]);
    v[0] = fmaf(acc[0], inv, bb.x); v[1] = fmaf(acc[1], inv, bb.y);
  }
  float s1 = 0.f, s2 = 0.f;
  #pragma unroll
  for (int e = 0; e < EPL; e++){ s1 += v[e]; s2 += v[e] * v[e]; }
  #pragma unroll
  for (int off = 32; off; off >>= 1){ s1 += __shfl_xor(s1, off); s2 += __shfl_xor(s2, off); }
  const float mu = s1 / DIM;
  const float rstd = rsqrtf(s2 / DIM - mu * mu + EPS_LN);

  if constexpr (EPL == 4){
    float4 gg = *reinterpret_cast<const float4*>(&gamma[lane * 4]);
    float4 be = *reinterpret_cast<const float4*>(&beta[lane * 4]);
    float o0 = fmaxf((v[0] - mu) * rstd * gg.x + be.x, 0.f);
    float o1 = fmaxf((v[1] - mu) * rstd * gg.y + be.y, 0.f);
    float o2 = fmaxf((v[2] - mu) * rstd * gg.z + be.z, 0.f);
    float o3 = fmaxf((v[3] - mu) * rstd * gg.w + be.w, 0.f);
    if constexpr (BF16_OUT){
      uint2 pk;
      pk.x = (uint)f2bf(o0) | ((uint)f2bf(o1) << 16);
      pk.y = (uint)f2bf(o2) | ((uint)f2bf(o3) << 16);
      *reinterpret_cast<uint2*>(&reinterpret_cast<ushort*>(out)[(size_t)n * DIM + lane * 4]) = pk;
    } else {
      *reinterpret_cast<float4*>(&out[(size_t)n * DIM + lane * 4]) = make_float4(o0, o1, o2, o3);
    }
  } else {
    float2 gg = *reinterpret_cast<const float2*>(&gamma[lane * 2]);
    float2 be = *reinterpret_cast<const float2*>(&beta[lane * 2]);
    float o0 = fmaxf((v[0] - mu) * rstd * gg.x + be.x, 0.f);
    float o1 = fmaxf((v[1] - mu) * rstd * gg.y + be.y, 0.f);
    if constexpr (BF16_OUT){
      uint pk = (uint)f2bf(o0) | ((uint)f2bf(o1) << 16);
      reinterpret_cast<uint*>(out)[(size_t)n * (DIM / 2) + lane] = pk;
    } else {
      *reinterpret_cast<float2*>(&out[(size_t)n * DIM + lane * 2]) = make_float2(o0, o1);
    }
  }
}

// ---------------- parallel pooling: Q chunks/graph, float4 lanes, no fences ----------------
__global__ __launch_bounds__(256) void k_pool(const float* __restrict__ h, const int* __restrict__ pos,
    float* __restrict__ pool_sum, uint* __restrict__ pool_max){
  const int t = (int)threadIdx.x;
  const int g = blockIdx.x / POOL_Q;
  const int q = blockIdx.x % POOL_Q;
  const int s = pos[g], e = pos[g + 1];
  const int len = e - s;
  if (len <= 0) return;
  const int chunk = (len + POOL_Q - 1) / POOL_Q;
  const int n0 = s + q * chunk;
  const int n1 = min(n0 + chunk, e);
  if (n0 >= n1) return;
  const int qd = t & 31;
  const int slot = t >> 5;
  const int wid = t >> 6;

  float4 sum = make_float4(0.f, 0.f, 0.f, 0.f);
  float4 mx  = make_float4(0.f, 0.f, 0.f, 0.f);
  for (int n = n0 + slot; n < n1; n += 8){
    float4 v = *reinterpret_cast<const float4*>(&h[(size_t)n * 128 + qd * 4]);
    sum.x += v.x; sum.y += v.y; sum.z += v.z; sum.w += v.w;
    mx.x = fmaxf(mx.x, v.x); mx.y = fmaxf(mx.y, v.y);
    mx.z = fmaxf(mx.z, v.z); mx.w = fmaxf(mx.w, v.w);
  }
  sum.x += __shfl_xor(sum.x, 32); sum.y += __shfl_xor(sum.y, 32);
  sum.z += __shfl_xor(sum.z, 32); sum.w += __shfl_xor(sum.w, 32);
  mx.x = fmaxf(mx.x, __shfl_xor(mx.x, 32)); mx.y = fmaxf(mx.y, __shfl_xor(mx.y, 32));
  mx.z = fmaxf(mx.z, __shfl_xor(mx.z, 32)); mx.w = fmaxf(mx.w, __shfl_xor(mx.w, 32));
  __shared__ float4 lsum[4][32], lmax[4][32];
  if ((t & 63) < 32){ lsum[wid][qd] = sum; lmax[wid][qd] = mx; }
  __syncthreads();
  if (t < 32){
    float4 S = lsum[0][t], M = lmax[0][t];
    #pragma unroll
    for (int w = 1; w < 4; w++){
      float4 S2 = lsum[w][t], M2 = lmax[w][t];
      S.x += S2.x; S.y += S2.y; S.z += S2.z; S.w += S2.w;
      M.x = fmaxf(M.x, M2.x); M.y = fmaxf(M.y, M2.y);
      M.z = fmaxf(M.z, M2.z); M.w = fmaxf(M.w, M2.w);
    }
    float* ps = &pool_sum[g * 128 + t * 4];
    uint*  pm = &pool_max[g * 128 + t * 4];
    atomicAdd(&ps[0], S.x); atomicAdd(&ps[1], S.y);
    atomicAdd(&ps[2], S.z); atomicAdd(&ps[3], S.w);
    atomicMax(&pm[0], __float_as_uint(M.x)); atomicMax(&pm[1], __float_as_uint(M.y));
    atomicMax(&pm[2], __float_as_uint(M.z)); atomicMax(&pm[3], __float_as_uint(M.w));
  }
}

// ---------------- final projection (kernel boundary = fence for pool atomics) ----------------
__global__ __launch_bounds__(128) void k_final(const float* __restrict__ pool_sum,
    const uint* __restrict__ pool_max, const int* __restrict__ pos,
    const float* __restrict__ Wp, const float* __restrict__ bp, float* __restrict__ out){
  const int g = blockIdx.x;
  const int j = (int)threadIdx.x;
  float inv = 1.f / fmaxf((float)(pos[g + 1] - pos[g]), 1.f);
  float acc = bp[j];
  #pragma unroll 4
  for (int k = 0; k < 128; k++)
    acc = fmaf(pool_sum[g * 128 + k] * inv, Wp[k * 128 + j], acc);
  #pragma unroll 4
  for (int k = 0; k < 128; k++)
    acc = fmaf(__uint_as_float(pool_max[g * 128 + k]), Wp[(128 + k) * 128 + j], acc);
  out[g * 128 + j] = acc;
}

// ---------------- launch ----------------
extern "C" void kernel_launch(void* const* d_in, const int* in_sizes, int n_in,
                              void* d_out, int out_size, void* d_ws, size_t ws_size,
                              hipStream_t stream){
  const float* x     = (const float*)d_in[0];
  const int*   ei    = (const int*)d_in[1];
  const int*   batch = (const int*)d_in[2];
  const float* W1    = (const float*)d_in[3];
  const float* asrc1 = (const float*)d_in[4];
  const float* adst1 = (const float*)d_in[5];
  const float* b1    = (const float*)d_in[6];
  const float* g1    = (const float*)d_in[7];
  const float* be1   = (const float*)d_in[8];
  const float* W2    = (const float*)d_in[9];
  const float* asrc2 = (const float*)d_in[10];
  const float* adst2 = (const float*)d_in[11];
  const float* b2    = (const float*)d_in[12];
  const float* g2    = (const float*)d_in[13];
  const float* be2   = (const float*)d_in[14];
  const float* W3    = (const float*)d_in[15];
  const float* asrc3 = (const float*)d_in[16];
  const float* adst3 = (const float*)d_in[17];
  const float* b3    = (const float*)d_in[18];
  const float* g3    = (const float*)d_in[19];
  const float* be3   = (const float*)d_in[20];
  const float* Wp    = (const float*)d_in[21];
  const float* bp    = (const float*)d_in[22];

  const int N = in_sizes[0] / 128;
  const int E = in_sizes[1] / 2;
  const int G = out_size / 128;
  const int EN = E + N;

  char* ws = (char*)d_ws;
  size_t off = 0;
  auto alloc = [&](size_t bytes) -> char* {
    char* p = ws + off;
    off = (off + bytes + 255) & ~(size_t)255;
    return p;
  };
  ushort*   region0  = (ushort*)alloc((size_t)N * 256 * 2);
  ushort*   x_bf     = region0;
  ushort*   h_bf     = region0;
  ushort*   xbufA    = (ushort*)alloc((size_t)N * 256 * 2);  // xl (bf16)
  float*    xbufB    = (float*)alloc((size_t)N * 128 * 4);   // layer-3 output (f32, pooling)
  float*    al       = (float*)alloc((size_t)N * 4 * 4);
  float*    ar       = (float*)alloc((size_t)N * 4 * 4);
  int*      deg      = (int*)alloc((size_t)N * 4);
  int*      row_ptr  = (int*)alloc((size_t)(N + 1) * 4);
  int*      cursor   = (int*)alloc((size_t)N * 4);
  int*      csr_src  = (int*)alloc((size_t)EN * 4);
  int*      pos      = (int*)alloc((size_t)(G + 1) * 4);
  float*    pool_sum = (float*)alloc((size_t)G * 128 * 4);
  uint*     pool_max = (uint*)alloc((size_t)G * 128 * 4);
  ushort*   W1t      = (ushort*)alloc((size_t)256 * 128 * 2);
  ushort*   W2t      = (ushort*)alloc((size_t)256 * 256 * 2);
  ushort*   W3t      = (ushort*)alloc((size_t)128 * 256 * 2);
  const int NB = (N + 1023) / 1024;
  int*      bsum     = (int*)alloc((size_t)NB * 4);

  hipMemsetAsync(deg, 0, (size_t)N * 4, stream);

  // CSR build + graph bounds + pool zeroing + dtype prep
  k_deg<<<(EN + 255) / 256, 256, 0, stream>>>(ei, deg, E, N);
  k_bsum<<<NB, 1024, 0, stream>>>(deg, bsum, N);
  k_misc<<<2 + (G * 128 + 255) / 256, 256, 0, stream>>>(bsum, NB, batch, pos, pool_sum, pool_max, N, G);
  k_scan2<<<NB, 1024, 0, stream>>>(deg, bsum, row_ptr, cursor, N);
  k_scatter<<<(EN + 255) / 256, 256, 0, stream>>>(ei, cursor, csr_src, E, N);
  {
    int total = N * 32 + 256 * 128 + 256 * 256 + 128 * 256;
    k_prep<<<(total + 255) / 256, 256, 0, stream>>>(x, x_bf, W1, W1t, W2, W2t, W3, W3t, N);
  }

  const int MB = (N + 127) / 128;
  const int NB4 = (N + 3) / 4;

  // Layer 1: 128 -> 256, H=4, C=64
  k_mm<128, 256, 4><<<dim3(MB, 2), 256, 0, stream>>>(x_bf, W1t, xbufA, asrc1, adst1, al, ar, N);
  k_aggw<4, 256, true><<<NB4, 256, 0, stream>>>(xbufA, al, ar, row_ptr, csr_src, b1, g1, be1, (float*)h_bf, N);

  // Layer 2: 256 -> 256, H=4, C=64
  k_mm<256, 256, 4><<<dim3(MB, 2), 256, 0, stream>>>(h_bf, W2t, xbufA, asrc2, adst2, al, ar, N);
  k_aggw<4, 256, true><<<NB4, 256, 0, stream>>>(xbufA, al, ar, row_ptr, csr_src, b2, g2, be2, (float*)h_bf, N);

  // Layer 3: 256 -> 128, H=1, C=128
  k_mm<256, 128, 1><<<dim3(MB, 1), 256, 0, stream>>>(h_bf, W3t, xbufA, asrc3, adst3, al, ar, N);
  k_aggw<1, 128, false><<<NB4, 256, 0, stream>>>(xbufA, al, ar, row_ptr, csr_src, b3, g3, be3, xbufB, N);

  // Pooling + final projection
  k_pool<<<G * POOL_Q, 256, 0, stream>>>(xbufB, pos, pool_sum, pool_max);
  k_final<<<G, 128, 0, stream>>>(pool_sum, pool_max, pos, Wp, bp, (float*)d_out);
}